// Round 1
// baseline (165.937 us; speedup 1.0000x reference)
//
#include <hip/hip_runtime.h>
#include <math.h>

// ---------------------------------------------------------------------------
// YOLOv5 head (R7): 3 kernels — KA eliminated via sole-writer restructuring.
// R6 observation: rocprof top-5 are ALL harness poison fills (256 MiB @ ~42us,
// 80% HBM peak); our kernels are each <41us. Controllable budget = kernel
// bodies + 4 graph-node launches. KA existed only to zero atomic counters /
// out and pack WT. This round:
//   KB: WT pack (strided, hidden in the 46 MB memory-bound GEMV pass)
//       + dense obj-logit GEMV (K split across threads + LDS reduce)
//       + per-BLOCK candidate regions (LDS atomic count, sole-writer count
//         store -> no pre-zeroed global counter needed)
//       + block 0 zeroes the 8 per-image counters (all KB blocks complete
//         before KC launches, so ordering is by kernel boundary)
//   KC: per-candidate 85-row scoring (lane=row, coalesced WT); walks the 700
//       block regions, each region split across 2 waves for balance
//   KD: per-image greedy NMS; writes its FULL 600-float slice (zero-fill on
//       early exit) so d_out needs no pre-zeroing.
// ---------------------------------------------------------------------------

#define IMG_F 640.0f

// ws layout (units: 4-byte words)
#define WT_F     0               // transposed weights [level][a][c][128]
#define N_WT     344064          //   row l innermost, pad l>=85 = 0
#define WT_L0    0               // 3*128*128
#define WT_L1    49152           // 3*256*128
#define WT_L2    147456          // 3*512*128
#define CNTB_F   344064          // 700 ints: per-KB-block candidate count
#define IMGCNT_F 344768          // 8 ints: per-image box count (KC atomics)
#define NSLOT    64              // candidate slots per KB block
#define CANDB_F  344776          // 700 x NSLOT x {code:int, obj:float}
#define IMGBUF_F (CANDB_F + 700 * NSLOT * 2)   // = 434376; 8 x CAP2 x 6 floats
#define CAP2     2048
// total = 532680 words ~= 2.1 MB of d_ws

#define LOGIT_T (-2.1972245773362196f)   // logit(0.1)

__constant__ float d_anch[3][3][2] = {
  {{6.1f,8.1f},{20.6f,12.6f},{11.2f,23.7f}},
  {{36.2f,26.8f},{25.9f,57.2f},{57.8f,47.9f}},
  {{122.1f,78.3f},{73.7f,143.8f},{236.1f,213.1f}},
};
__constant__ float d_stridec[3] = {8.f,16.f,32.f};

// ------------- KB: WT pack + dense obj GEMV + per-block candidates ---------
// Block covers Q quads (4 consecutive positions each) x full K; thread
// (q, slice) loads 16 channels x float4. Sole writer per position =>
// threshold + candidate push fused for all levels.
//   L0: blocks [0,400):   Q=32, S=8   (C=128, HW=6400)
//   L1: blocks [400,600): Q=16, S=16  (C=256, HW=1600)
//   L2: blocks [600,700): Q=8,  S=32  (C=512, HW=400)
__global__ __launch_bounds__(256) void kb_obj(
    const float* __restrict__ f0, const float* __restrict__ f1,
    const float* __restrict__ f2,
    const float* __restrict__ w0, const float* __restrict__ w1,
    const float* __restrict__ w2,
    const float* __restrict__ b0, const float* __restrict__ b1,
    const float* __restrict__ b2, float* __restrict__ ws) {
  __shared__ float red[3104];            // max S*(Q*12+1) over levels
  __shared__ int lcnt;
  int b = blockIdx.x, t = threadIdx.x;
  if (t == 0) lcnt = 0;
  if (b == 0 && t < 8) ((int*)ws)[IMGCNT_F + t] = 0;   // visible before KC
  // WT pack: transposed weights wT[level][a][c][128], row l innermost,
  // pad l>=85 -> 0. Writes coalesced; scattered reads absorbed by L2.
  // 344064 words over 700x256 threads = 2 strided iterations; hidden
  // inside this memory-bound kernel.
  for (int i = b * 256 + t; i < N_WT; i += 700 * 256) {
    int C, i2; const float* w;
    if (i < WT_L1)      { C = 128; i2 = i;         w = w0; }
    else if (i < WT_L2) { C = 256; i2 = i - WT_L1; w = w1; }
    else                { C = 512; i2 = i - WT_L2; w = w2; }
    int a = i2 / (C * 128);
    int r = i2 - a * (C * 128);
    int c = r >> 7, l = r & 127;
    ws[WT_F + i] = (l < 85) ? w[(size_t)(a * 85 + l) * C + c] : 0.f;
  }
  int level, Q, lq, S, bq0, C, HW;
  const float *f, *w, *bb;
  if (b < 400)      { level = 0; Q = 32; lq = 5; S = 8;  bq0 = b * 32;         C = 128; HW = 6400; f = f0; w = w0; bb = b0; }
  else if (b < 600) { level = 1; Q = 16; lq = 4; S = 16; bq0 = (b - 400) * 16; C = 256; HW = 1600; f = f1; w = w1; bb = b1; }
  else              { level = 2; Q = 8;  lq = 3; S = 32; bq0 = (b - 600) * 8;  C = 512; HW = 400;  f = f2; w = w2; bb = b2; }
  int q = t & (Q - 1), sl = t >> lq;
  int qpi = HW >> 2;
  int gq = bq0 + q;
  int n = gq / qpi;
  int sq = (gq - n * qpi) << 2;
  int kbase = sl * 16;                   // C/S == 16 for all levels
  const float* fp = f + ((size_t)(n * C + kbase)) * HW + sq;
  const float* wp = w + 4 * C + kbase;   // obj row for a=0; a=1:+85C; a=2:+170C
  float acc[3][4] = {{0.f,0.f,0.f,0.f},{0.f,0.f,0.f,0.f},{0.f,0.f,0.f,0.f}};
  #pragma unroll
  for (int c = 0; c < 16; ++c) {
    float4 v = *(const float4*)(fp + (size_t)c * HW);   // 16 B/lane coalesced
    float wa0 = wp[c];
    float wa1 = wp[85 * C + c];
    float wa2 = wp[170 * C + c];
    acc[0][0] = fmaf(v.x, wa0, acc[0][0]); acc[0][1] = fmaf(v.y, wa0, acc[0][1]);
    acc[0][2] = fmaf(v.z, wa0, acc[0][2]); acc[0][3] = fmaf(v.w, wa0, acc[0][3]);
    acc[1][0] = fmaf(v.x, wa1, acc[1][0]); acc[1][1] = fmaf(v.y, wa1, acc[1][1]);
    acc[1][2] = fmaf(v.z, wa1, acc[1][2]); acc[1][3] = fmaf(v.w, wa1, acc[1][3]);
    acc[2][0] = fmaf(v.x, wa2, acc[2][0]); acc[2][1] = fmaf(v.y, wa2, acc[2][1]);
    acc[2][2] = fmaf(v.z, wa2, acc[2][2]); acc[2][3] = fmaf(v.w, wa2, acc[2][3]);
  }
  // LDS: red[sl*(Q*12+1) + q*12 + a*4+p]; +1 pad => slice stride is odd,
  // conflict-free strided reduction reads.
  int stride = Q * 12 + 1;
  int base = sl * stride + q * 12;
  #pragma unroll
  for (int a = 0; a < 3; ++a)
    #pragma unroll
    for (int p = 0; p < 4; ++p)
      red[base + a * 4 + p] = acc[a][p];
  __syncthreads();                       // also covers lcnt init
  for (int r = t; r < Q * 12; r += 256) {
    int qq = r / 12, ap = r - qq * 12;
    int a = ap >> 2, p = ap & 3;
    float sum = 0.f;
    for (int s2 = 0; s2 < S; ++s2) sum += red[s2 * stride + qq * 12 + ap];
    float logit = sum + bb[a * 85 + 4];
    if (logit > LOGIT_T) {               // sigmoid(x)>0.1 <=> x>logit(0.1)
      float obj = 1.f / (1.f + expf(-logit));
      int gq2 = bq0 + qq;
      int n2 = gq2 / qpi;
      int s = ((gq2 - n2 * qpi) << 2) + p;
      int idx = atomicAdd(&lcnt, 1);     // LDS atomic, no global contention
      if (idx < NSLOT) {
        int* cd = (int*)ws + CANDB_F + (b * NSLOT + idx) * 2;
        cd[0] = (n2 << 24) | (level << 20) | (a << 16) | s;
        ((float*)cd)[1] = obj;
      }
    }
  }
  __syncthreads();
  if (t == 0) ((int*)ws)[CNTB_F + b] = min(lcnt, NSLOT);  // sole writer
}

// -------- KC: one wave per candidate, lane = output row, coalesced WT ------
template<int C, int HW, int Wd>
__device__ __forceinline__ void kc_cand(
    int level, int n, int a, int s, float obj,
    const float* __restrict__ f, const float* __restrict__ wTl,
    const float* __restrict__ bb, float* __restrict__ ws,
    float* __restrict__ fc, int lane) {
  #pragma unroll
  for (int j = 0; j < C / 64; ++j)
    fc[lane + 64 * j] = f[((size_t)(n * C + lane + 64 * j)) * HW + s];
  const float* wA = wTl + (size_t)a * C * 128;
  float acc1 = 0.f, acc2 = 0.f;          // rows: lane, 64+lane (pad rows = 0)
  #pragma unroll 8
  for (int c = 0; c < C; ++c) {
    float fv = fc[c];                    // LDS broadcast, conflict-free
    const float* wl = wA + c * 128;
    acc1 = fmaf(fv, wl[lane], acc1);     // coalesced 64 consecutive floats
    acc2 = fmaf(fv, wl[64 + lane], acc2);
  }
  acc1 += bb[a * 85 + lane];             // rows 0..63 all valid
  float sig1 = 1.f / (1.f + expf(-acc1));
  float sig2 = 0.f;
  if (lane < 21) {                       // rows 64..84
    acc2 += bb[a * 85 + 64 + lane];
    sig2 = 1.f / (1.f + expf(-acc2));
  }
  float p0 = __shfl(sig1, 0, 64), p1 = __shfl(sig1, 1, 64);
  float p2 = __shfl(sig1, 2, 64), p3 = __shfl(sig1, 3, 64);
  int gx = s % Wd, gy = s / Wd;
  float st = d_stridec[level];
  float cx = (2.f * p0 - 0.5f + (float)gx) * st;
  float cy = (2.f * p1 - 0.5f + (float)gy) * st;
  float bw = 4.f * p2 * p2 * d_anch[level][a][0];
  float bh = 4.f * p3 * p3 * d_anch[level][a][1];
  float x1 = fminf(fmaxf(cx - bw * 0.5f, 0.f), IMG_F);
  float y1 = fminf(fmaxf(cy - bh * 0.5f, 0.f), IMG_F);
  float x2 = fminf(fmaxf(cx + bw * 0.5f, 0.f), IMG_F);
  float y2 = fminf(fmaxf(cy + bh * 0.5f, 0.f), IMG_F);
  #pragma unroll
  for (int half = 0; half < 2; ++half) {
    bool on = half == 0 ? (lane >= 5) : (lane < 21);
    float sc = obj * (half == 0 ? sig1 : sig2);
    int cls = half == 0 ? (lane - 5) : (59 + lane);
    if (on && sc > 0.1f) {
      int p = atomicAdd((int*)ws + IMGCNT_F + n, 1);
      if (p < CAP2) {
        float* dst = ws + IMGBUF_F + ((size_t)(n * CAP2 + p)) * 6;
        dst[0] = x1; dst[1] = y1; dst[2] = x2; dst[3] = y2;
        dst[4] = sc; dst[5] = (float)cls;
      }
    }
  }
}

__global__ __launch_bounds__(256) void kc_score(
    const float* __restrict__ f0, const float* __restrict__ f1,
    const float* __restrict__ f2,
    const float* __restrict__ b0, const float* __restrict__ b1,
    const float* __restrict__ b2, float* __restrict__ ws) {
  __shared__ float fcol[4][512];
  int wv = threadIdx.x >> 6, lane = threadIdx.x & 63;
  // 512 wave slots walk 700 block regions; each region is split across 2
  // waves (phase = candidate parity) so the L2-heavy regions balance.
  int slot = blockIdx.x * 4 + wv;
  int reg0 = slot >> 1, ph = slot & 1;
  for (int reg = reg0; reg < 700; reg += 256) {
    int cnt = min(((int*)ws)[CNTB_F + reg], NSLOT);
    for (int ci = ph; ci < cnt; ci += 2) {
      int* cd = (int*)ws + CANDB_F + (reg * NSLOT + ci) * 2;
      int code = cd[0]; float obj = ((float*)cd)[1];
      int n = code >> 24, level = (code >> 20) & 15, a = (code >> 16) & 3, s = code & 0xFFFF;
      if (level == 0)
        kc_cand<128, 6400, 80>(0, n, a, s, obj, f0, ws + WT_F + WT_L0, b0, ws, fcol[wv], lane);
      else if (level == 1)
        kc_cand<256, 1600, 40>(1, n, a, s, obj, f1, ws + WT_F + WT_L1, b1, ws, fcol[wv], lane);
      else
        kc_cand<512, 400, 20>(2, n, a, s, obj, f2, ws + WT_F + WT_L2, b2, ws, fcol[wv], lane);
    }
  }
}

// ------------------------------------------ KD: per-image greedy NMS -------
// Writes its ENTIRE 600-float output slice (zero rows on early exit), so
// d_out needs no pre-zeroing kernel.
__global__ __launch_bounds__(256) void kd_nms(
    const float* __restrict__ ws, float* __restrict__ out,
    const float* __restrict__ sfp) {
  __shared__ float bx1[CAP2], by1[CAP2], bx2[CAP2], by2[CAP2], bsc[CAP2], blb[CAP2];
  __shared__ int bval[CAP2];
  __shared__ float rs[256];
  __shared__ int ri[256];
  int n = blockIdx.x, tid = threadIdx.x;
  int cnt = min(((const int*)ws)[IMGCNT_F + n], CAP2);
  for (int i = tid; i < cnt; i += 256) {
    const float* src = ws + IMGBUF_F + ((size_t)(n * CAP2 + i)) * 6;
    bx1[i] = src[0]; by1[i] = src[1]; bx2[i] = src[2]; by2[i] = src[3];
    bsc[i] = src[4]; blb[i] = src[5]; bval[i] = 1;
  }
  __syncthreads();
  float sf = sfp[n];
  for (int it = 0; it < 100; ++it) {
    float best = -1.f; int bi = -1;
    for (int i = tid; i < cnt; i += 256)
      if (bval[i] && bsc[i] > best) { best = bsc[i]; bi = i; }
    rs[tid] = best; ri[tid] = bi;
    __syncthreads();
    for (int off = 128; off > 0; off >>= 1) {
      if (tid < off && rs[tid + off] > rs[tid]) { rs[tid] = rs[tid + off]; ri[tid] = ri[tid + off]; }
      __syncthreads();
    }
    int wi = ri[0]; float wsc = rs[0];
    if (wi < 0) {                         // no valid left: stays empty forever
      for (int r2 = it * 6 + tid; r2 < 600; r2 += 256)
        out[(size_t)n * 600 + r2] = 0.f;  // zero-fill remaining rows
      break;
    }
    if (tid == 0) {
      float* o = out + (size_t)(n * 100 + it) * 6;
      o[0] = bx1[wi] / sf; o[1] = by1[wi] / sf;
      o[2] = bx2[wi] / sf; o[3] = by2[wi] / sf;
      o[4] = wsc;          o[5] = blb[wi];
    }
    // suppress IoU > 0.6 on class-offset boxes (offset adds to all 4 coords)
    float ofw = blb[wi] * IMG_F;
    float wx1 = bx1[wi] + ofw, wy1 = by1[wi] + ofw;
    float wx2 = bx2[wi] + ofw, wy2 = by2[wi] + ofw;
    float wa = (wx2 - wx1) * (wy2 - wy1);
    for (int i = tid; i < cnt; i += 256) {
      if (bval[i]) {
        float o2 = blb[i] * IMG_F;
        float x1 = bx1[i] + o2, y1 = by1[i] + o2, x2 = bx2[i] + o2, y2 = by2[i] + o2;
        float iw = fmaxf(fminf(wx2, x2) - fmaxf(wx1, x1), 0.f);
        float ih = fmaxf(fminf(wy2, y2) - fmaxf(wy1, y1), 0.f);
        float inter = iw * ih;
        float area = (x2 - x1) * (y2 - y1);
        float iou = inter / (wa + area - inter + 1e-7f);
        if (iou > 0.6f) bval[i] = 0;
      }
    }
    if (tid == 0) bval[wi] = 0;
    __syncthreads();
  }
}

// ---------------------------------------------------------------------------
extern "C" void kernel_launch(void* const* d_in, const int* in_sizes, int n_in,
                              void* d_out, int out_size, void* d_ws, size_t ws_size,
                              hipStream_t stream) {
  // setup_inputs() dict order: f0,w0,b0, f1,w1,b1, f2,w2,b2, scale_factors
  const float* f0 = (const float*)d_in[0];
  const float* w0 = (const float*)d_in[1];
  const float* b0 = (const float*)d_in[2];
  const float* f1 = (const float*)d_in[3];
  const float* w1 = (const float*)d_in[4];
  const float* b1 = (const float*)d_in[5];
  const float* f2 = (const float*)d_in[6];
  const float* w2 = (const float*)d_in[7];
  const float* b2 = (const float*)d_in[8];
  const float* sf = (const float*)d_in[9];
  float* out = (float*)d_out;
  float* ws  = (float*)d_ws;    // needs ~2.1 MB

  kb_obj  <<<700, 256, 0, stream>>>(f0, f1, f2, w0, w1, w2, b0, b1, b2, ws);
  kc_score<<<128, 256, 0, stream>>>(f0, f1, f2, b0, b1, b2, ws);
  kd_nms  <<<8,   256, 0, stream>>>(ws, out, sf);
}

// Round 2
// 126.460 us; speedup vs baseline: 1.3122x; 1.3122x over previous
//
#include <hip/hip_runtime.h>
#include <math.h>

// ---------------------------------------------------------------------------
// YOLOv5 head (R8): fix KC latency-boundedness.
// R7 post-mortem: kc_score = 67 us with Occupancy 1%, HBM 1.3%, VALU 0.7% --
// pure latency bound. ~284 candidates on ~200 wave-slots, each a serial
// C=512 c-loop of L2/IC-latency loads (~13 us/candidate, no latency hiding).
// R8: BLOCK-per-candidate KC:
//   - 256 threads/candidate; f-column staged in LDS by all threads
//   - c-dim split across the 4 waves (chain C/4 <= 128 iters, unroll 8)
//   - lanes cover the 128 output rows via float2 (coalesced 512 B/wave/c)
//   - LDS reduce (4 partials/row) -> sigmoid -> box + class push
//   - grid = 700 regions x 8 slot-phases = 5600 blocks, no compaction:
//     empty blocks load one cached count int and exit; active blocks map
//     ~1:1 to candidates (region overflow handled by ci += 8 stepping).
// KB (dense obj GEMV + WT pack + per-block candidate regions) and KD (NMS)
// unchanged from R7 (passed, not dominant).
// ---------------------------------------------------------------------------

#define IMG_F 640.0f

// ws layout (units: 4-byte words)
#define WT_F     0               // transposed weights [level][a][c][128]
#define N_WT     344064          //   row l innermost, pad l>=85 = 0
#define WT_L0    0               // 3*128*128
#define WT_L1    49152           // 3*256*128
#define WT_L2    147456          // 3*512*128
#define CNTB_F   344064          // 700 ints: per-KB-block candidate count
#define IMGCNT_F 344768          // 8 ints: per-image box count (KC atomics)
#define NSLOT    64              // candidate slots per KB block
#define CANDB_F  344776          // 700 x NSLOT x {code:int, obj:float}
#define IMGBUF_F (CANDB_F + 700 * NSLOT * 2)   // = 434376; 8 x CAP2 x 6 floats
#define CAP2     2048
// total = 532680 words ~= 2.1 MB of d_ws

#define LOGIT_T (-2.1972245773362196f)   // logit(0.1)

__constant__ float d_anch[3][3][2] = {
  {{6.1f,8.1f},{20.6f,12.6f},{11.2f,23.7f}},
  {{36.2f,26.8f},{25.9f,57.2f},{57.8f,47.9f}},
  {{122.1f,78.3f},{73.7f,143.8f},{236.1f,213.1f}},
};
__constant__ float d_stridec[3] = {8.f,16.f,32.f};

// ------------- KB: WT pack + dense obj GEMV + per-block candidates ---------
// Block covers Q quads (4 consecutive positions each) x full K; thread
// (q, slice) loads 16 channels x float4. Sole writer per position =>
// threshold + candidate push fused for all levels.
//   L0: blocks [0,400):   Q=32, S=8   (C=128, HW=6400)
//   L1: blocks [400,600): Q=16, S=16  (C=256, HW=1600)
//   L2: blocks [600,700): Q=8,  S=32  (C=512, HW=400)
__global__ __launch_bounds__(256) void kb_obj(
    const float* __restrict__ f0, const float* __restrict__ f1,
    const float* __restrict__ f2,
    const float* __restrict__ w0, const float* __restrict__ w1,
    const float* __restrict__ w2,
    const float* __restrict__ b0, const float* __restrict__ b1,
    const float* __restrict__ b2, float* __restrict__ ws) {
  __shared__ float red[3104];            // max S*(Q*12+1) over levels
  __shared__ int lcnt;
  int b = blockIdx.x, t = threadIdx.x;
  if (t == 0) lcnt = 0;
  if (b == 0 && t < 8) ((int*)ws)[IMGCNT_F + t] = 0;   // visible before KC
  // WT pack: transposed weights wT[level][a][c][128], row l innermost,
  // pad l>=85 -> 0. Writes coalesced; scattered reads absorbed by L2.
  for (int i = b * 256 + t; i < N_WT; i += 700 * 256) {
    int C, i2; const float* w;
    if (i < WT_L1)      { C = 128; i2 = i;         w = w0; }
    else if (i < WT_L2) { C = 256; i2 = i - WT_L1; w = w1; }
    else                { C = 512; i2 = i - WT_L2; w = w2; }
    int a = i2 / (C * 128);
    int r = i2 - a * (C * 128);
    int c = r >> 7, l = r & 127;
    ws[WT_F + i] = (l < 85) ? w[(size_t)(a * 85 + l) * C + c] : 0.f;
  }
  int level, Q, lq, S, bq0, C, HW;
  const float *f, *w, *bb;
  if (b < 400)      { level = 0; Q = 32; lq = 5; S = 8;  bq0 = b * 32;         C = 128; HW = 6400; f = f0; w = w0; bb = b0; }
  else if (b < 600) { level = 1; Q = 16; lq = 4; S = 16; bq0 = (b - 400) * 16; C = 256; HW = 1600; f = f1; w = w1; bb = b1; }
  else              { level = 2; Q = 8;  lq = 3; S = 32; bq0 = (b - 600) * 8;  C = 512; HW = 400;  f = f2; w = w2; bb = b2; }
  int q = t & (Q - 1), sl = t >> lq;
  int qpi = HW >> 2;
  int gq = bq0 + q;
  int n = gq / qpi;
  int sq = (gq - n * qpi) << 2;
  int kbase = sl * 16;                   // C/S == 16 for all levels
  const float* fp = f + ((size_t)(n * C + kbase)) * HW + sq;
  const float* wp = w + 4 * C + kbase;   // obj row for a=0; a=1:+85C; a=2:+170C
  float acc[3][4] = {{0.f,0.f,0.f,0.f},{0.f,0.f,0.f,0.f},{0.f,0.f,0.f,0.f}};
  #pragma unroll
  for (int c = 0; c < 16; ++c) {
    float4 v = *(const float4*)(fp + (size_t)c * HW);   // 16 B/lane coalesced
    float wa0 = wp[c];
    float wa1 = wp[85 * C + c];
    float wa2 = wp[170 * C + c];
    acc[0][0] = fmaf(v.x, wa0, acc[0][0]); acc[0][1] = fmaf(v.y, wa0, acc[0][1]);
    acc[0][2] = fmaf(v.z, wa0, acc[0][2]); acc[0][3] = fmaf(v.w, wa0, acc[0][3]);
    acc[1][0] = fmaf(v.x, wa1, acc[1][0]); acc[1][1] = fmaf(v.y, wa1, acc[1][1]);
    acc[1][2] = fmaf(v.z, wa1, acc[1][2]); acc[1][3] = fmaf(v.w, wa1, acc[1][3]);
    acc[2][0] = fmaf(v.x, wa2, acc[2][0]); acc[2][1] = fmaf(v.y, wa2, acc[2][1]);
    acc[2][2] = fmaf(v.z, wa2, acc[2][2]); acc[2][3] = fmaf(v.w, wa2, acc[2][3]);
  }
  // LDS: red[sl*(Q*12+1) + q*12 + a*4+p]; +1 pad => slice stride is odd,
  // conflict-free strided reduction reads.
  int stride = Q * 12 + 1;
  int base = sl * stride + q * 12;
  #pragma unroll
  for (int a = 0; a < 3; ++a)
    #pragma unroll
    for (int p = 0; p < 4; ++p)
      red[base + a * 4 + p] = acc[a][p];
  __syncthreads();                       // also covers lcnt init
  for (int r = t; r < Q * 12; r += 256) {
    int qq = r / 12, ap = r - qq * 12;
    int a = ap >> 2, p = ap & 3;
    float sum = 0.f;
    for (int s2 = 0; s2 < S; ++s2) sum += red[s2 * stride + qq * 12 + ap];
    float logit = sum + bb[a * 85 + 4];
    if (logit > LOGIT_T) {               // sigmoid(x)>0.1 <=> x>logit(0.1)
      float obj = 1.f / (1.f + expf(-logit));
      int gq2 = bq0 + qq;
      int n2 = gq2 / qpi;
      int s = ((gq2 - n2 * qpi) << 2) + p;
      int idx = atomicAdd(&lcnt, 1);     // LDS atomic, no global contention
      if (idx < NSLOT) {
        int* cd = (int*)ws + CANDB_F + (b * NSLOT + idx) * 2;
        cd[0] = (n2 << 24) | (level << 20) | (a << 16) | s;
        ((float*)cd)[1] = obj;
      }
    }
  }
  __syncthreads();
  if (t == 0) ((int*)ws)[CNTB_F + b] = min(lcnt, NSLOT);  // sole writer
}

// -------- KC: one BLOCK per candidate, c-split across waves ---------------
// out[l] = sum_c f[n,c,s] * wT[a][c][l].  Wave sl owns c-quarter
// [sl*C/4,(sl+1)*C/4); lane covers rows {2*lane, 2*lane+1} via float2
// (coalesced 512 B per wave per c). LDS reduce of 4 partials per row,
// then sigmoid + box + class-threshold push.
template<int C, int HW, int Wd>
__device__ __forceinline__ void kc_block(
    int level, int n, int a, int s, float obj,
    const float* __restrict__ f, const float* __restrict__ wTl,
    const float* __restrict__ bb, float* __restrict__ ws,
    float* __restrict__ fc, float* __restrict__ partial,
    float* __restrict__ sig, int tid) {
  for (int i = tid; i < C; i += 256)               // stage f column
    fc[i] = f[((size_t)(n * C + i)) * HW + s];
  __syncthreads();
  int sl = tid >> 6, lane = tid & 63;
  const float* wA = wTl + (size_t)a * C * 128;
  constexpr int CQ = C / 4;
  const float* wp = wA + (size_t)(sl * CQ) * 128;
  const float* fq = fc + sl * CQ;
  float2 acc = {0.f, 0.f};
  #pragma unroll 8
  for (int c = 0; c < CQ; ++c) {
    float fv = fq[c];                              // LDS broadcast
    float2 wv = *(const float2*)(wp + (size_t)c * 128 + 2 * lane);
    acc.x = fmaf(fv, wv.x, acc.x);
    acc.y = fmaf(fv, wv.y, acc.y);
  }
  *(float2*)(partial + sl * 128 + 2 * lane) = acc;
  __syncthreads();
  if (tid < 85) {
    float sum = partial[tid] + partial[128 + tid] + partial[256 + tid] + partial[384 + tid];
    float logit = sum + bb[a * 85 + tid];
    sig[tid] = 1.f / (1.f + expf(-logit));
  }
  __syncthreads();
  float p0 = sig[0], p1 = sig[1], p2 = sig[2], p3 = sig[3];
  int gx = s % Wd, gy = s / Wd;
  float st = d_stridec[level];
  float cx = (2.f * p0 - 0.5f + (float)gx) * st;
  float cy = (2.f * p1 - 0.5f + (float)gy) * st;
  float bw = 4.f * p2 * p2 * d_anch[level][a][0];
  float bh = 4.f * p3 * p3 * d_anch[level][a][1];
  float x1 = fminf(fmaxf(cx - bw * 0.5f, 0.f), IMG_F);
  float y1 = fminf(fmaxf(cy - bh * 0.5f, 0.f), IMG_F);
  float x2 = fminf(fmaxf(cx + bw * 0.5f, 0.f), IMG_F);
  float y2 = fminf(fmaxf(cy + bh * 0.5f, 0.f), IMG_F);
  if (tid >= 5 && tid < 85) {                      // classes 0..79
    float sc = obj * sig[tid];
    if (sc > 0.1f) {
      int p = atomicAdd((int*)ws + IMGCNT_F + n, 1);
      if (p < CAP2) {
        float* dst = ws + IMGBUF_F + ((size_t)(n * CAP2 + p)) * 6;
        dst[0] = x1; dst[1] = y1; dst[2] = x2; dst[3] = y2;
        dst[4] = sc; dst[5] = (float)(tid - 5);
      }
    }
  }
  __syncthreads();                                 // LDS reuse across items
}

__global__ __launch_bounds__(256) void kc_score(
    const float* __restrict__ f0, const float* __restrict__ f1,
    const float* __restrict__ f2,
    const float* __restrict__ b0, const float* __restrict__ b1,
    const float* __restrict__ b2, float* __restrict__ ws) {
  __shared__ float fc[512];
  __shared__ float partial[512];
  __shared__ float sig[85];
  int tid = threadIdx.x;
  int reg = blockIdx.x >> 3, ci0 = blockIdx.x & 7;  // grid = 700*8
  int cnt = min(((int*)ws)[CNTB_F + reg], NSLOT);
  for (int ci = ci0; ci < cnt; ci += 8) {           // uniform per block
    int* cd = (int*)ws + CANDB_F + (reg * NSLOT + ci) * 2;
    int code = cd[0]; float obj = ((float*)cd)[1];
    int n = code >> 24, level = (code >> 20) & 15, a = (code >> 16) & 3, s = code & 0xFFFF;
    if (level == 0)
      kc_block<128, 6400, 80>(0, n, a, s, obj, f0, ws + WT_F + WT_L0, b0, ws, fc, partial, sig, tid);
    else if (level == 1)
      kc_block<256, 1600, 40>(1, n, a, s, obj, f1, ws + WT_F + WT_L1, b1, ws, fc, partial, sig, tid);
    else
      kc_block<512, 400, 20>(2, n, a, s, obj, f2, ws + WT_F + WT_L2, b2, ws, fc, partial, sig, tid);
  }
}

// ------------------------------------------ KD: per-image greedy NMS -------
// Writes its ENTIRE 600-float output slice (zero rows on early exit), so
// d_out needs no pre-zeroing kernel.
__global__ __launch_bounds__(256) void kd_nms(
    const float* __restrict__ ws, float* __restrict__ out,
    const float* __restrict__ sfp) {
  __shared__ float bx1[CAP2], by1[CAP2], bx2[CAP2], by2[CAP2], bsc[CAP2], blb[CAP2];
  __shared__ int bval[CAP2];
  __shared__ float rs[256];
  __shared__ int ri[256];
  int n = blockIdx.x, tid = threadIdx.x;
  int cnt = min(((const int*)ws)[IMGCNT_F + n], CAP2);
  for (int i = tid; i < cnt; i += 256) {
    const float* src = ws + IMGBUF_F + ((size_t)(n * CAP2 + i)) * 6;
    bx1[i] = src[0]; by1[i] = src[1]; bx2[i] = src[2]; by2[i] = src[3];
    bsc[i] = src[4]; blb[i] = src[5]; bval[i] = 1;
  }
  __syncthreads();
  float sf = sfp[n];
  for (int it = 0; it < 100; ++it) {
    float best = -1.f; int bi = -1;
    for (int i = tid; i < cnt; i += 256)
      if (bval[i] && bsc[i] > best) { best = bsc[i]; bi = i; }
    rs[tid] = best; ri[tid] = bi;
    __syncthreads();
    for (int off = 128; off > 0; off >>= 1) {
      if (tid < off && rs[tid + off] > rs[tid]) { rs[tid] = rs[tid + off]; ri[tid] = ri[tid + off]; }
      __syncthreads();
    }
    int wi = ri[0]; float wsc = rs[0];
    if (wi < 0) {                         // no valid left: stays empty forever
      for (int r2 = it * 6 + tid; r2 < 600; r2 += 256)
        out[(size_t)n * 600 + r2] = 0.f;  // zero-fill remaining rows
      break;
    }
    if (tid == 0) {
      float* o = out + (size_t)(n * 100 + it) * 6;
      o[0] = bx1[wi] / sf; o[1] = by1[wi] / sf;
      o[2] = bx2[wi] / sf; o[3] = by2[wi] / sf;
      o[4] = wsc;          o[5] = blb[wi];
    }
    // suppress IoU > 0.6 on class-offset boxes (offset adds to all 4 coords)
    float ofw = blb[wi] * IMG_F;
    float wx1 = bx1[wi] + ofw, wy1 = by1[wi] + ofw;
    float wx2 = bx2[wi] + ofw, wy2 = by2[wi] + ofw;
    float wa = (wx2 - wx1) * (wy2 - wy1);
    for (int i = tid; i < cnt; i += 256) {
      if (bval[i]) {
        float o2 = blb[i] * IMG_F;
        float x1 = bx1[i] + o2, y1 = by1[i] + o2, x2 = bx2[i] + o2, y2 = by2[i] + o2;
        float iw = fmaxf(fminf(wx2, x2) - fmaxf(wx1, x1), 0.f);
        float ih = fmaxf(fminf(wy2, y2) - fmaxf(wy1, y1), 0.f);
        float inter = iw * ih;
        float area = (x2 - x1) * (y2 - y1);
        float iou = inter / (wa + area - inter + 1e-7f);
        if (iou > 0.6f) bval[i] = 0;
      }
    }
    if (tid == 0) bval[wi] = 0;
    __syncthreads();
  }
}

// ---------------------------------------------------------------------------
extern "C" void kernel_launch(void* const* d_in, const int* in_sizes, int n_in,
                              void* d_out, int out_size, void* d_ws, size_t ws_size,
                              hipStream_t stream) {
  // setup_inputs() dict order: f0,w0,b0, f1,w1,b1, f2,w2,b2, scale_factors
  const float* f0 = (const float*)d_in[0];
  const float* w0 = (const float*)d_in[1];
  const float* b0 = (const float*)d_in[2];
  const float* f1 = (const float*)d_in[3];
  const float* w1 = (const float*)d_in[4];
  const float* b1 = (const float*)d_in[5];
  const float* f2 = (const float*)d_in[6];
  const float* w2 = (const float*)d_in[7];
  const float* b2 = (const float*)d_in[8];
  const float* sf = (const float*)d_in[9];
  float* out = (float*)d_out;
  float* ws  = (float*)d_ws;    // needs ~2.1 MB

  kb_obj  <<<700,    256, 0, stream>>>(f0, f1, f2, w0, w1, w2, b0, b1, b2, ws);
  kc_score<<<700 * 8, 256, 0, stream>>>(f0, f1, f2, b0, b1, b2, ws);
  kd_nms  <<<8,      256, 0, stream>>>(ws, out, sf);
}